// Round 1
// 8894.000 us; speedup vs baseline: 2.0856x; 2.0856x over previous
//
#include <hip/hip_runtime.h>
#include <math.h>

#define NN 10000
#define NE 160000
#define TSTEPS 64
#define FIN 16
#define HID 128
#define TC 8          // GCN timestep chunk
#define NB 40         // LSTM nodes per block (10000 / 250)
#define NBLK 250

// ---- workspace element offsets (floats/ints, all 4B) ----
#define OFF_DINV   0ul
#define OFF_DEG    16384ul
#define OFF_ROWPTR 32768ul
#define OFF_CURSOR 49152ul
#define OFF_CSRC   65536ul
#define OFF_CSRW   (OFF_CSRC + (size_t)NE)
#define OFF_WZT    (OFF_CSRW + (size_t)NE)
#define OFF_WHT    (OFF_WZT + 131072ul)
#define OFF_WCT    (OFF_WHT + 16384ul)
#define OFF_HBUF   (OFF_WCT + 16384ul)
#define OFF_CBUF   (OFF_HBUF + (size_t)NN*HID)
#define OFF_BUFA   (OFF_CBUF + (size_t)NN*HID)
#define OFF_BUFB   (OFF_BUFA + (size_t)TC*NN*HID)

__device__ __forceinline__ float sigf(float x){ return 1.f/(1.f + expf(-x)); }

// ---- weight transposes: WzT[j*512+k] = [Wih;Whh][k][j], WhT/WcT [j*128+k] ----
__global__ void k_transpose(const float* __restrict__ Wih, const float* __restrict__ Whh,
                            const float* __restrict__ Wh,  const float* __restrict__ Wc,
                            float* __restrict__ WzT, float* __restrict__ WhT, float* __restrict__ WcT){
  int idx = blockIdx.x*blockDim.x + threadIdx.x;   // 0..65535
  int k = idx >> 7;        // 0..511
  int j = idx & 127;       // 0..127
  WzT[(size_t)j*512 + k]        = Wih[(size_t)k*HID + j];
  WzT[(size_t)(HID+j)*512 + k]  = Whh[(size_t)k*HID + j];
  if (k < HID){
    WhT[(size_t)j*HID + k] = Wh[(size_t)k*HID + j];
    WcT[(size_t)j*HID + k] = Wc[(size_t)k*HID + j];
  }
}

__global__ void k_degcount(const int* __restrict__ edges, int* __restrict__ degcnt){
  int e = blockIdx.x*blockDim.x + threadIdx.x;
  if (e < NE) atomicAdd(&degcnt[edges[NE + e]], 1);
}

__global__ void k_dinv(const int* __restrict__ degcnt, float* __restrict__ dinv){
  int n = blockIdx.x*blockDim.x + threadIdx.x;
  if (n < NN) dinv[n] = rsqrtf((float)(degcnt[n] + 1));   // +1 self loop, always >=1
}

// single-block scan: rowptr[0]=0, rowptr[n+1]=sum(degcnt[0..n])
__global__ void k_scan(const int* __restrict__ degcnt, int* __restrict__ rowptr){
  __shared__ int sd[1024];
  __shared__ int carry;
  if (threadIdx.x == 0){ carry = 0; rowptr[0] = 0; }
  __syncthreads();
  for (int base = 0; base < NN; base += 1024){
    int i = base + threadIdx.x;
    int v = (i < NN) ? degcnt[i] : 0;
    sd[threadIdx.x] = v;
    __syncthreads();
    for (int off = 1; off < 1024; off <<= 1){
      int t = (threadIdx.x >= off) ? sd[threadIdx.x - off] : 0;
      __syncthreads();
      sd[threadIdx.x] += t;
      __syncthreads();
    }
    int incl = sd[threadIdx.x] + carry;
    if (i < NN) rowptr[i+1] = incl;
    __syncthreads();
    if (threadIdx.x == 1023) carry = incl;
    __syncthreads();
  }
}

__global__ void k_csrfill(const int* __restrict__ edges, const int* __restrict__ rowptr,
                          int* __restrict__ cursor, int* __restrict__ csrc, float* __restrict__ csrw,
                          const float* __restrict__ dinv){
  int e = blockIdx.x*blockDim.x + threadIdx.x;
  if (e >= NE) return;
  int s = edges[e];
  int d = edges[NE + e];
  int pos = rowptr[d] + atomicAdd(&cursor[d], 1);
  csrc[pos] = s;
  csrw[pos] = dinv[s] * dinv[d];
}

// x_t @ W1 for a chunk of TC timesteps: bufA[tt][n][j]
__global__ void k_gemm1(const float* __restrict__ inputs, const float* __restrict__ W1,
                        float* __restrict__ out, int c0){
  int idx = blockIdx.x*256 + threadIdx.x;    // TC*NN*HID total
  int j  = idx & 127;
  int n  = (idx >> 7) % NN;
  int tt = idx / (NN*HID);
  int t  = c0 + tt;
  const float* x = inputs + (size_t)n*TSTEPS*FIN + (size_t)t*FIN;
  float acc = 0.f;
  #pragma unroll
  for (int f = 0; f < FIN; f++) acc += x[f] * W1[f*HID + j];
  out[(size_t)tt*NN*HID + (size_t)n*HID + j] = acc;
}

// CSR gather aggregate + self loop + bias + relu: bufB[tt][n][j]
__global__ void k_agg_relu(const float* __restrict__ hbuf, const int* __restrict__ rowptr,
                           const int* __restrict__ csrc, const float* __restrict__ csrw,
                           const float* __restrict__ dinv, const float* __restrict__ b1,
                           float* __restrict__ out){
  int n = blockIdx.x, tt = blockIdx.y, j = threadIdx.x;
  const float* hb = hbuf + (size_t)tt*NN*HID;
  float dn = dinv[n];
  float acc = hb[(size_t)n*HID + j] * (dn*dn);
  int beg = rowptr[n], end = rowptr[n+1];
  for (int k = beg; k < end; k++){
    int s = csrc[k]; float w = csrw[k];
    acc += hb[(size_t)s*HID + j] * w;
  }
  acc += b1[j];
  out[(size_t)tt*NN*HID + (size_t)n*HID + j] = fmaxf(acc, 0.f);
}

// [rows,128] @ W[128,128] (j-major, x@W orientation)
__global__ void k_gemm2(const float* __restrict__ X, const float* __restrict__ W,
                        float* __restrict__ out){
  int k = threadIdx.x;                       // 128
  size_t r0 = (size_t)blockIdx.x * 16;
  float acc[16];
  #pragma unroll
  for (int m = 0; m < 16; m++) acc[m] = 0.f;
  const float* xp = X + r0*HID;
  for (int j = 0; j < HID; j++){
    float w = W[j*HID + k];
    #pragma unroll
    for (int m = 0; m < 16; m++) acc[m] += xp[(size_t)m*HID + j] * w;
  }
  #pragma unroll
  for (int m = 0; m < 16; m++) out[(r0+m)*HID + k] = acc[m];
}

// aggregate layer-2 + b2, then LayerNorm(ln2); writes g into d_out series slot [n,t,:]
__global__ void k_agg_ln(const float* __restrict__ hbuf, const int* __restrict__ rowptr,
                         const int* __restrict__ csrc, const float* __restrict__ csrw,
                         const float* __restrict__ dinv, const float* __restrict__ b2,
                         const float* __restrict__ ln2g, const float* __restrict__ ln2b,
                         float* __restrict__ outg, int c0){
  __shared__ float sb[4];
  int n = blockIdx.x, tt = blockIdx.y, j = threadIdx.x;
  const float* hb = hbuf + (size_t)tt*NN*HID;
  float dn = dinv[n];
  float acc = hb[(size_t)n*HID + j] * (dn*dn);
  int beg = rowptr[n], end = rowptr[n+1];
  for (int k = beg; k < end; k++){
    int s = csrc[k]; float w = csrw[k];
    acc += hb[(size_t)s*HID + j] * w;
  }
  acc += b2[j];
  // LayerNorm over 128 lanes (2 waves)
  float s1 = acc, s2 = acc*acc;
  #pragma unroll
  for (int off = 32; off; off >>= 1){
    s1 += __shfl_down(s1, off, 64);
    s2 += __shfl_down(s2, off, 64);
  }
  if ((j & 63) == 0){ sb[j>>6] = s1; sb[(j>>6)+2] = s2; }
  __syncthreads();
  float sum = sb[0]+sb[1], sum2 = sb[2]+sb[3];
  float mean = sum * (1.f/128.f);
  float var  = sum2 * (1.f/128.f) - mean*mean;
  float rs   = rsqrtf(var + 1e-5f);
  int t = c0 + tt;
  outg[(size_t)n*TSTEPS*HID + (size_t)t*HID + j] = (acc - mean)*rs*ln2g[j] + ln2b[j];
}

// ---------------------------------------------------------------------------
// Persistent fused LSTM: one block owns NB=40 nodes for all 64 timesteps.
// The recurrence couples only within a node, so no grid sync is needed.
// LDS: g double-buffer 2*40*128 | h 40*128 | z 40*512  = 143360 B total.
// Per step: stage-load g(t+1) early (regs) -> GEMM (VALU-bound, acc[40]/thread)
//           -> z to LDS -> write-late g(t+1) -> barrier -> pointwise+LN
//           (row in one wave, 2 vals/lane, butterfly reduce) -> barrier.
// series slot t is read (as g) one step before it is overwritten -> safe.
// ---------------------------------------------------------------------------
__global__ __launch_bounds__(512, 2)
void k_lstm_fused(float* series,                       // d_out: in=g[n][t][128], out=LN1(h)
                  const float* __restrict__ WzT,       // [256][512] j-major (Wih^T ; Whh^T)
                  const float* __restrict__ bih, const float* __restrict__ bhh,
                  const float* __restrict__ ln1g, const float* __restrict__ ln1b,
                  float* __restrict__ hOut, float* __restrict__ cOut){
  extern __shared__ float smem[];
  float* gb = smem;                 // [2][NB][128]
  float* hs = smem + 2*NB*HID;      // [NB][128]
  float* zs = smem + 3*NB*HID;      // [NB][512]

  const int k  = threadIdx.x;       // 0..511 : z column in GEMM phase
  const int n0 = blockIdx.x * NB;
  const int w  = k >> 6;            // wave 0..7
  const int l  = k & 63;            // lane

  // per-thread constants
  const float bsum = bih[k] + bhh[k];
  const float lg0 = ln1g[l], lg1 = ln1g[64+l];
  const float lb0 = ln1b[l], lb1 = ln1b[64+l];

  float creg[10];
  #pragma unroll
  for (int i = 0; i < 10; i++) creg[i] = 0.f;

  // h0 = 0
  #pragma unroll
  for (int i = 0; i < 10; i++) hs[i*512 + k] = 0.f;

  // stage g(0)
  #pragma unroll
  for (int i = 0; i < 10; i++){
    int flat = i*512 + k; int m = flat >> 7; int j = flat & 127;
    gb[flat] = series[(size_t)(n0+m)*TSTEPS*HID + j];
  }
  __syncthreads();

  for (int t = 0; t < TSTEPS; t++){
    const float* gcur = gb + (t & 1)*(NB*HID);

    // T14: issue next-step g loads early, write to LDS late
    float pre[10];
    const bool has_next = (t + 1 < TSTEPS);
    if (has_next){
      #pragma unroll
      for (int i = 0; i < 10; i++){
        int flat = i*512 + k; int m = flat >> 7; int j = flat & 127;
        pre[i] = series[(size_t)(n0+m)*TSTEPS*HID + (size_t)(t+1)*HID + j];
      }
    }

    // ---- GEMM: z[m][k] = bsum + sum_j g[m][j]*Wih[k][j] + h[m][j]*Whh[k][j]
    float acc[NB];
    #pragma unroll
    for (int m = 0; m < NB; m++) acc[m] = bsum;

    for (int j4 = 0; j4 < HID/4; j4++){
      const int j = j4*4;
      const float wi0 = WzT[(size_t)(j+0)*512 + k];
      const float wi1 = WzT[(size_t)(j+1)*512 + k];
      const float wi2 = WzT[(size_t)(j+2)*512 + k];
      const float wi3 = WzT[(size_t)(j+3)*512 + k];
      const float wh0 = WzT[(size_t)(HID+j+0)*512 + k];
      const float wh1 = WzT[(size_t)(HID+j+1)*512 + k];
      const float wh2 = WzT[(size_t)(HID+j+2)*512 + k];
      const float wh3 = WzT[(size_t)(HID+j+3)*512 + k];
      #pragma unroll
      for (int m = 0; m < NB; m++){
        const float4 gv = *(const float4*)(gcur + m*HID + j);
        const float4 hv = *(const float4*)(hs   + m*HID + j);
        acc[m] += gv.x*wi0 + gv.y*wi1 + gv.z*wi2 + gv.w*wi3
                + hv.x*wh0 + hv.y*wh1 + hv.z*wh2 + hv.w*wh3;
      }
    }
    #pragma unroll
    for (int m = 0; m < NB; m++) zs[m*512 + k] = acc[m];

    if (has_next){
      float* gn = gb + ((t+1) & 1)*(NB*HID);
      #pragma unroll
      for (int i = 0; i < 10; i++) gn[i*512 + k] = pre[i];
    }
    __syncthreads();   // z ready; all GEMM reads of hs done

    // ---- pointwise + LN1; wave w owns rows m = w*5 + r, lane l holds j=l and j=64+l
    #pragma unroll
    for (int r = 0; r < 5; r++){
      const int m = w*5 + r;
      const float* zr = zs + m*512;
      const float zi0 = zr[      l], zi1 = zr[ 64 + l];
      const float zf0 = zr[128 + l], zf1 = zr[192 + l];
      const float zg0 = zr[256 + l], zg1 = zr[320 + l];
      const float zo0 = zr[384 + l], zo1 = zr[448 + l];
      const float c0n = sigf(zf0)*creg[2*r]   + sigf(zi0)*tanhf(zg0);
      const float c1n = sigf(zf1)*creg[2*r+1] + sigf(zi1)*tanhf(zg1);
      const float h0 = sigf(zo0)*tanhf(c0n);
      const float h1 = sigf(zo1)*tanhf(c1n);
      creg[2*r]   = c0n;
      creg[2*r+1] = c1n;
      hs[m*HID + l]      = h0;
      hs[m*HID + 64 + l] = h1;
      // barrier-free LN: row lives in this wave (2 values/lane), butterfly reduce
      float s1 = h0 + h1, s2 = h0*h0 + h1*h1;
      #pragma unroll
      for (int off = 1; off < 64; off <<= 1){
        s1 += __shfl_xor(s1, off, 64);
        s2 += __shfl_xor(s2, off, 64);
      }
      const float mean = s1 * (1.f/128.f);
      const float var  = s2 * (1.f/128.f) - mean*mean;
      const float rs   = rsqrtf(var + 1e-5f);
      const size_t ob  = (size_t)(n0+m)*TSTEPS*HID + (size_t)t*HID;
      series[ob + l]      = (h0 - mean)*rs*lg0 + lb0;
      series[ob + 64 + l] = (h1 - mean)*rs*lg1 + lb1;
      if (t == TSTEPS-1){
        hOut[(size_t)(n0+m)*HID + l]      = h0;
        hOut[(size_t)(n0+m)*HID + 64 + l] = h1;
        cOut[(size_t)(n0+m)*HID + l]      = c0n;
        cOut[(size_t)(n0+m)*HID + 64 + l] = c1n;
      }
    }
    __syncthreads();   // hs(t+1-ready), g prefetch landed
  }
}

// out[n,k] = act(b[k] + X[n,:]@WT[:,k]); WT is [128,128] j-major
__global__ void k_final_gemm(const float* __restrict__ X, const float* __restrict__ WT,
                             const float* __restrict__ b, float* __restrict__ out, int do_tanh){
  int k = threadIdx.x;
  size_t n0 = (size_t)blockIdx.x * 16;
  float acc[16];
  float bb = b[k];
  #pragma unroll
  for (int m = 0; m < 16; m++) acc[m] = bb;
  const float* xp = X + n0*HID;
  for (int j = 0; j < HID; j++){
    float w = WT[j*HID + k];
    #pragma unroll
    for (int m = 0; m < 16; m++) acc[m] += xp[(size_t)m*HID + j] * w;
  }
  #pragma unroll
  for (int m = 0; m < 16; m++){
    float v = acc[m];
    if (do_tanh) v = tanhf(v);
    out[(n0+m)*HID + k] = v;
  }
}

extern "C" void kernel_launch(void* const* d_in, const int* in_sizes, int n_in,
                              void* d_out, int out_size, void* d_ws, size_t ws_size,
                              hipStream_t stream){
  const float* inputs = (const float*)d_in[0];
  const int*   edges  = (const int*)  d_in[1];
  const float* W1  = (const float*)d_in[2];
  const float* b1  = (const float*)d_in[3];
  const float* W2  = (const float*)d_in[4];
  const float* b2  = (const float*)d_in[5];
  const float* Wih = (const float*)d_in[6];
  const float* Whh = (const float*)d_in[7];
  const float* bih = (const float*)d_in[8];
  const float* bhh = (const float*)d_in[9];
  const float* ln1g = (const float*)d_in[10];
  const float* ln1b = (const float*)d_in[11];
  const float* ln2g = (const float*)d_in[12];
  const float* ln2b = (const float*)d_in[13];
  const float* Wh  = (const float*)d_in[14];
  const float* bh  = (const float*)d_in[15];
  const float* Wc  = (const float*)d_in[16];
  const float* bc  = (const float*)d_in[17];

  float* out = (float*)d_out;
  float* ws  = (float*)d_ws;

  float* dinv   = ws + OFF_DINV;
  int*   degcnt = (int*)(ws + OFF_DEG);
  int*   rowptr = (int*)(ws + OFF_ROWPTR);
  int*   cursor = (int*)(ws + OFF_CURSOR);
  int*   csrc   = (int*)(ws + OFF_CSRC);
  float* csrw   = ws + OFF_CSRW;
  float* WzT    = ws + OFF_WZT;
  float* WhT    = ws + OFF_WHT;
  float* WcT    = ws + OFF_WCT;
  float* hbuf   = ws + OFF_HBUF;
  float* cbuf   = ws + OFF_CBUF;
  float* bufA   = ws + OFF_BUFA;
  float* bufB   = ws + OFF_BUFB;

  // persistent LSTM kernel needs 140 KB dynamic LDS (>64 KB default cap)
  static int lds_attr_set = 0;
  if (!lds_attr_set){
    hipFuncSetAttribute(reinterpret_cast<const void*>(k_lstm_fused),
                        hipFuncAttributeMaxDynamicSharedMemorySize, 143360);
    lds_attr_set = 1;
  }

  hipMemsetAsync(degcnt, 0, NN*sizeof(int), stream);
  hipMemsetAsync(cursor, 0, NN*sizeof(int), stream);

  k_transpose<<<256, 256, 0, stream>>>(Wih, Whh, Wh, Wc, WzT, WhT, WcT);
  k_degcount<<<(NE+255)/256, 256, 0, stream>>>(edges, degcnt);
  k_dinv<<<(NN+255)/256, 256, 0, stream>>>(degcnt, dinv);
  k_scan<<<1, 1024, 0, stream>>>(degcnt, rowptr);
  k_csrfill<<<(NE+255)/256, 256, 0, stream>>>(edges, rowptr, cursor, csrc, csrw, dinv);

  // ---- GCN, chunked over timesteps; g (post-LN2) written into d_out series region ----
  for (int c0 = 0; c0 < TSTEPS; c0 += TC){
    k_gemm1<<<(TC*NN*HID)/256, 256, 0, stream>>>(inputs, W1, bufA, c0);
    k_agg_relu<<<dim3(NN, TC), 128, 0, stream>>>(bufA, rowptr, csrc, csrw, dinv, b1, bufB);
    k_gemm2<<<(TC*NN)/16, 128, 0, stream>>>(bufB, W2, bufA);
    k_agg_ln<<<dim3(NN, TC), 128, 0, stream>>>(bufA, rowptr, csrc, csrw, dinv, b2, ln2g, ln2b, out, c0);
  }

  // ---- LSTM over time: ONE persistent kernel (node-parallel recurrence) ----
  k_lstm_fused<<<NBLK, 512, 143360, stream>>>(out, WzT, bih, bhh, ln1g, ln1b, hbuf, cbuf);

  // ---- final projections ----
  float* outHidden = out + (size_t)NN*TSTEPS*HID;
  float* outCell   = outHidden + (size_t)NN*HID;
  k_final_gemm<<<NN/16, 128, 0, stream>>>(hbuf, WhT, bh, outHidden, 1);
  k_final_gemm<<<NN/16, 128, 0, stream>>>(cbuf, WcT, bc, outCell, 0);
}

// Round 2
// 8004.128 us; speedup vs baseline: 2.3174x; 1.1112x over previous
//
#include <hip/hip_runtime.h>
#include <math.h>

#define NN 10000
#define NE 160000
#define TSTEPS 64
#define FIN 16
#define HID 128
#define TC 8          // GCN timestep chunk
#define NB 20         // LSTM nodes per block
#define RPT 5         // rows per thread (NB / 4 mg-groups)
#define NBLK 500      // NN / NB

// ---- workspace element offsets (floats/ints, all 4B) ----
#define OFF_DINV   0ul
#define OFF_DEG    16384ul
#define OFF_ROWPTR 32768ul
#define OFF_CURSOR 49152ul
#define OFF_CSRC   65536ul
#define OFF_CSRW   (OFF_CSRC + (size_t)NE)
#define OFF_WZT    (OFF_CSRW + (size_t)NE)
#define OFF_WHT    (OFF_WZT + 131072ul)
#define OFF_WCT    (OFF_WHT + 16384ul)
#define OFF_HBUF   (OFF_WCT + 16384ul)
#define OFF_CBUF   (OFF_HBUF + (size_t)NN*HID)
#define OFF_BUFA   (OFF_CBUF + (size_t)NN*HID + 16384ul)
#define OFF_BUFB   (OFF_BUFA + (size_t)TC*NN*HID)

__device__ __forceinline__ float sigf(float x){ return 1.f/(1.f + expf(-x)); }

// ---- weight layouts ----
// WzT2[(j*128 + kg)*4 + q] = Wih[q*128+kg][j]          (j in 0..127)
// WzT2[((128+j)*128 + kg)*4 + q] = Whh[q*128+kg][j]    (j in 0..127)
// so a thread owning column group kg reads ONE float4 per j covering all 4 gates.
// WhT/WcT stay [j*128 + k] (j-major) for the final projections.
__global__ void k_transpose(const float* __restrict__ Wih, const float* __restrict__ Whh,
                            const float* __restrict__ Wh,  const float* __restrict__ Wc,
                            float* __restrict__ WzT2, float* __restrict__ WhT, float* __restrict__ WcT){
  int idx = blockIdx.x*blockDim.x + threadIdx.x;   // 0..65535
  int k = idx >> 7;        // 0..511  (= q*128 + kg)
  int j = idx & 127;       // 0..127
  int q  = k >> 7;         // gate 0..3
  int kg = k & 127;        // column within gate
  WzT2[((size_t)j*128 + kg)*4 + q]        = Wih[(size_t)k*HID + j];
  WzT2[((size_t)(128+j)*128 + kg)*4 + q]  = Whh[(size_t)k*HID + j];
  if (k < HID){
    WhT[(size_t)j*HID + k] = Wh[(size_t)k*HID + j];
    WcT[(size_t)j*HID + k] = Wc[(size_t)k*HID + j];
  }
}

__global__ void k_degcount(const int* __restrict__ edges, int* __restrict__ degcnt){
  int e = blockIdx.x*blockDim.x + threadIdx.x;
  if (e < NE) atomicAdd(&degcnt[edges[NE + e]], 1);
}

__global__ void k_dinv(const int* __restrict__ degcnt, float* __restrict__ dinv){
  int n = blockIdx.x*blockDim.x + threadIdx.x;
  if (n < NN) dinv[n] = rsqrtf((float)(degcnt[n] + 1));   // +1 self loop, always >=1
}

// single-block scan: rowptr[0]=0, rowptr[n+1]=sum(degcnt[0..n])
__global__ void k_scan(const int* __restrict__ degcnt, int* __restrict__ rowptr){
  __shared__ int sd[1024];
  __shared__ int carry;
  if (threadIdx.x == 0){ carry = 0; rowptr[0] = 0; }
  __syncthreads();
  for (int base = 0; base < NN; base += 1024){
    int i = base + threadIdx.x;
    int v = (i < NN) ? degcnt[i] : 0;
    sd[threadIdx.x] = v;
    __syncthreads();
    for (int off = 1; off < 1024; off <<= 1){
      int t = (threadIdx.x >= off) ? sd[threadIdx.x - off] : 0;
      __syncthreads();
      sd[threadIdx.x] += t;
      __syncthreads();
    }
    int incl = sd[threadIdx.x] + carry;
    if (i < NN) rowptr[i+1] = incl;
    __syncthreads();
    if (threadIdx.x == 1023) carry = incl;
    __syncthreads();
  }
}

__global__ void k_csrfill(const int* __restrict__ edges, const int* __restrict__ rowptr,
                          int* __restrict__ cursor, int* __restrict__ csrc, float* __restrict__ csrw,
                          const float* __restrict__ dinv){
  int e = blockIdx.x*blockDim.x + threadIdx.x;
  if (e >= NE) return;
  int s = edges[e];
  int d = edges[NE + e];
  int pos = rowptr[d] + atomicAdd(&cursor[d], 1);
  csrc[pos] = s;
  csrw[pos] = dinv[s] * dinv[d];
}

// x_t @ W1 for a chunk of TC timesteps: bufA[tt][n][j]
__global__ void k_gemm1(const float* __restrict__ inputs, const float* __restrict__ W1,
                        float* __restrict__ out, int c0){
  int idx = blockIdx.x*256 + threadIdx.x;    // TC*NN*HID total
  int j  = idx & 127;
  int n  = (idx >> 7) % NN;
  int tt = idx / (NN*HID);
  int t  = c0 + tt;
  const float* x = inputs + (size_t)n*TSTEPS*FIN + (size_t)t*FIN;
  float acc = 0.f;
  #pragma unroll
  for (int f = 0; f < FIN; f++) acc += x[f] * W1[f*HID + j];
  out[(size_t)tt*NN*HID + (size_t)n*HID + j] = acc;
}

// CSR gather aggregate + self loop + bias + relu: bufB[tt][n][j]
__global__ void k_agg_relu(const float* __restrict__ hbuf, const int* __restrict__ rowptr,
                           const int* __restrict__ csrc, const float* __restrict__ csrw,
                           const float* __restrict__ dinv, const float* __restrict__ b1,
                           float* __restrict__ out){
  int n = blockIdx.x, tt = blockIdx.y, j = threadIdx.x;
  const float* hb = hbuf + (size_t)tt*NN*HID;
  float dn = dinv[n];
  float acc = hb[(size_t)n*HID + j] * (dn*dn);
  int beg = rowptr[n], end = rowptr[n+1];
  for (int k = beg; k < end; k++){
    int s = csrc[k]; float w = csrw[k];
    acc += hb[(size_t)s*HID + j] * w;
  }
  acc += b1[j];
  out[(size_t)tt*NN*HID + (size_t)n*HID + j] = fmaxf(acc, 0.f);
}

// [rows,128] @ W[128,128] (j-major, x@W orientation)
__global__ void k_gemm2(const float* __restrict__ X, const float* __restrict__ W,
                        float* __restrict__ out){
  int k = threadIdx.x;                       // 128
  size_t r0 = (size_t)blockIdx.x * 16;
  float acc[16];
  #pragma unroll
  for (int m = 0; m < 16; m++) acc[m] = 0.f;
  const float* xp = X + r0*HID;
  for (int j = 0; j < HID; j++){
    float w = W[j*HID + k];
    #pragma unroll
    for (int m = 0; m < 16; m++) acc[m] += xp[(size_t)m*HID + j] * w;
  }
  #pragma unroll
  for (int m = 0; m < 16; m++) out[(r0+m)*HID + k] = acc[m];
}

// aggregate layer-2 + b2, then LayerNorm(ln2); writes g into d_out series slot [n,t,:]
__global__ void k_agg_ln(const float* __restrict__ hbuf, const int* __restrict__ rowptr,
                         const int* __restrict__ csrc, const float* __restrict__ csrw,
                         const float* __restrict__ dinv, const float* __restrict__ b2,
                         const float* __restrict__ ln2g, const float* __restrict__ ln2b,
                         float* __restrict__ outg, int c0){
  __shared__ float sb[4];
  int n = blockIdx.x, tt = blockIdx.y, j = threadIdx.x;
  const float* hb = hbuf + (size_t)tt*NN*HID;
  float dn = dinv[n];
  float acc = hb[(size_t)n*HID + j] * (dn*dn);
  int beg = rowptr[n], end = rowptr[n+1];
  for (int k = beg; k < end; k++){
    int s = csrc[k]; float w = csrw[k];
    acc += hb[(size_t)s*HID + j] * w;
  }
  acc += b2[j];
  // LayerNorm over 128 lanes (2 waves)
  float s1 = acc, s2 = acc*acc;
  #pragma unroll
  for (int off = 32; off; off >>= 1){
    s1 += __shfl_down(s1, off, 64);
    s2 += __shfl_down(s2, off, 64);
  }
  if ((j & 63) == 0){ sb[j>>6] = s1; sb[(j>>6)+2] = s2; }
  __syncthreads();
  float sum = sb[0]+sb[1], sum2 = sb[2]+sb[3];
  float mean = sum * (1.f/128.f);
  float var  = sum2 * (1.f/128.f) - mean*mean;
  float rs   = rsqrtf(var + 1e-5f);
  int t = c0 + tt;
  outg[(size_t)n*TSTEPS*HID + (size_t)t*HID + j] = (acc - mean)*rs*ln2g[j] + ln2b[j];
}

// ---------------------------------------------------------------------------
// Persistent fused LSTM v2: gate-interleaved columns, pointwise in-register.
// Thread (kg, mg): owns output cols {kg,128+kg,256+kg,384+kg} for rows
// m = mg*RPT..mg*RPT+RPT-1. One broadcast ds_read_b128 feeds 16 FMAs
// (4x fewer LDS reads than v1); z never touches LDS; LDS = 31 KB ->
// 2 blocks/CU, 4 waves/SIMD. LN row spans a wave pair: 64-lane butterfly
// + 2-float LDS partial exchange.
// ---------------------------------------------------------------------------
__global__ __launch_bounds__(512, 4)
void k_lstm_fused(float* series,                       // d_out: in=g[n][t][128], out=LN1(h)
                  const float* __restrict__ WzT2,      // [256][128][4] gate-interleaved
                  const float* __restrict__ bih, const float* __restrict__ bhh,
                  const float* __restrict__ ln1g, const float* __restrict__ ln1b,
                  float* __restrict__ hOut, float* __restrict__ cOut){
  extern __shared__ float smem[];
  float* gb = smem;                 // [2][NB][128] = 5120 f
  float* hs = smem + 2*NB*HID;      // [NB][128]    = 2560 f
  float* sb = smem + 3*NB*HID;      // [8 waves][RPT][2] = 80 f

  const int tid = threadIdx.x;
  const int kg  = tid & 127;        // column within gate
  const int mg  = tid >> 7;         // row group 0..3
  const int wv  = tid >> 6;         // wave 0..7
  const int n0  = blockIdx.x * NB;

  const float4* wg4 = (const float4*)WzT2;       // g-part rows j=0..127
  const float4* wh4 = wg4 + 128*128;             // h-part rows

  float4 bs;
  bs.x = bih[      kg] + bhh[      kg];
  bs.y = bih[128 + kg] + bhh[128 + kg];
  bs.z = bih[256 + kg] + bhh[256 + kg];
  bs.w = bih[384 + kg] + bhh[384 + kg];
  const float lg = ln1g[kg], lb = ln1b[kg];

  float creg[RPT];
  #pragma unroll
  for (int r = 0; r < RPT; r++) creg[r] = 0.f;

  // h0 = 0
  #pragma unroll
  for (int i = 0; i < RPT; i++) hs[i*512 + tid] = 0.f;

  // stage g(0)
  #pragma unroll
  for (int i = 0; i < RPT; i++){
    int flat = i*512 + tid; int m = flat >> 7; int j = flat & 127;
    gb[flat] = series[(size_t)(n0+m)*TSTEPS*HID + j];
  }
  __syncthreads();

  for (int t = 0; t < TSTEPS; t++){
    const float* gcur = gb + (t & 1)*(NB*HID);

    // issue next-step g loads early; LDS-write them late (T14)
    float pre[RPT];
    const bool has_next = (t + 1 < TSTEPS);
    if (has_next){
      #pragma unroll
      for (int i = 0; i < RPT; i++){
        int flat = i*512 + tid; int m = flat >> 7; int j = flat & 127;
        pre[i] = series[(size_t)(n0+m)*TSTEPS*HID + (size_t)(t+1)*HID + j];
      }
    }

    float acc[RPT][4];
    #pragma unroll
    for (int r = 0; r < RPT; r++){
      acc[r][0] = 0.f; acc[r][1] = 0.f; acc[r][2] = 0.f; acc[r][3] = 0.f;
    }

    // ---- GEMM g-part: acc[r][q] += sum_j g[m][j] * Wih[q*128+kg][j]
    for (int j4 = 0; j4 < 32; j4++){
      const int j = j4*4;
      const float4 w0 = wg4[(size_t)(j+0)*128 + kg];
      const float4 w1 = wg4[(size_t)(j+1)*128 + kg];
      const float4 w2 = wg4[(size_t)(j+2)*128 + kg];
      const float4 w3 = wg4[(size_t)(j+3)*128 + kg];
      #pragma unroll
      for (int r = 0; r < RPT; r++){
        const float4 gv = *(const float4*)(gcur + (mg*RPT + r)*HID + j);
        acc[r][0] += gv.x*w0.x + gv.y*w1.x + gv.z*w2.x + gv.w*w3.x;
        acc[r][1] += gv.x*w0.y + gv.y*w1.y + gv.z*w2.y + gv.w*w3.y;
        acc[r][2] += gv.x*w0.z + gv.y*w1.z + gv.z*w2.z + gv.w*w3.z;
        acc[r][3] += gv.x*w0.w + gv.y*w1.w + gv.z*w2.w + gv.w*w3.w;
      }
    }
    // ---- GEMM h-part: acc[r][q] += sum_j h[m][j] * Whh[q*128+kg][j]
    for (int j4 = 0; j4 < 32; j4++){
      const int j = j4*4;
      const float4 w0 = wh4[(size_t)(j+0)*128 + kg];
      const float4 w1 = wh4[(size_t)(j+1)*128 + kg];
      const float4 w2 = wh4[(size_t)(j+2)*128 + kg];
      const float4 w3 = wh4[(size_t)(j+3)*128 + kg];
      #pragma unroll
      for (int r = 0; r < RPT; r++){
        const float4 hv4 = *(const float4*)(hs + (mg*RPT + r)*HID + j);
        acc[r][0] += hv4.x*w0.x + hv4.y*w1.x + hv4.z*w2.x + hv4.w*w3.x;
        acc[r][1] += hv4.x*w0.y + hv4.y*w1.y + hv4.z*w2.y + hv4.w*w3.y;
        acc[r][2] += hv4.x*w0.z + hv4.y*w1.z + hv4.z*w2.z + hv4.w*w3.z;
        acc[r][3] += hv4.x*w0.w + hv4.y*w1.w + hv4.z*w2.w + hv4.w*w3.w;
      }
    }
    __syncthreads();   // all reads of hs/gcur done

    // ---- pointwise + per-wave LN partials (all in registers)
    float hv[RPT];
    #pragma unroll
    for (int r = 0; r < RPT; r++){
      const int m = mg*RPT + r;
      const float zi = acc[r][0] + bs.x;
      const float zf = acc[r][1] + bs.y;
      const float zg = acc[r][2] + bs.z;
      const float zo = acc[r][3] + bs.w;
      const float cn = sigf(zf)*creg[r] + sigf(zi)*tanhf(zg);
      const float hn = sigf(zo)*tanhf(cn);
      creg[r] = cn;
      hv[r] = hn;
      hs[m*HID + kg] = hn;
      float s1 = hn, s2 = hn*hn;
      #pragma unroll
      for (int off = 1; off < 64; off <<= 1){
        s1 += __shfl_xor(s1, off, 64);
        s2 += __shfl_xor(s2, off, 64);
      }
      if ((tid & 63) == 0){
        sb[wv*(RPT*2) + r*2    ] = s1;
        sb[wv*(RPT*2) + r*2 + 1] = s2;
      }
    }
    // land the g(t+1) prefetch
    if (has_next){
      float* gn = gb + ((t+1) & 1)*(NB*HID);
      #pragma unroll
      for (int i = 0; i < RPT; i++) gn[i*512 + tid] = pre[i];
    }
    __syncthreads();   // hs, sb, gn visible

    // ---- LN combine across the wave pair + series write
    #pragma unroll
    for (int r = 0; r < RPT; r++){
      const int m = mg*RPT + r;
      const float s1 = sb[(2*mg  )*(RPT*2) + r*2    ] + sb[(2*mg+1)*(RPT*2) + r*2    ];
      const float s2 = sb[(2*mg  )*(RPT*2) + r*2 + 1] + sb[(2*mg+1)*(RPT*2) + r*2 + 1];
      const float mean = s1 * (1.f/128.f);
      const float var  = s2 * (1.f/128.f) - mean*mean;
      const float rs   = rsqrtf(var + 1e-5f);
      series[(size_t)(n0+m)*TSTEPS*HID + (size_t)t*HID + kg] = (hv[r] - mean)*rs*lg + lb;
    }
    if (t == TSTEPS-1){
      #pragma unroll
      for (int r = 0; r < RPT; r++){
        const int m = mg*RPT + r;
        hOut[(size_t)(n0+m)*HID + kg] = hv[r];
        cOut[(size_t)(n0+m)*HID + kg] = creg[r];
      }
    }
  }
}

// out[n,k] = act(b[k] + X[n,:]@WT[:,k]); WT is [128,128] j-major
__global__ void k_final_gemm(const float* __restrict__ X, const float* __restrict__ WT,
                             const float* __restrict__ b, float* __restrict__ out, int do_tanh){
  int k = threadIdx.x;
  size_t n0 = (size_t)blockIdx.x * 16;
  float acc[16];
  float bb = b[k];
  #pragma unroll
  for (int m = 0; m < 16; m++) acc[m] = bb;
  const float* xp = X + n0*HID;
  for (int j = 0; j < HID; j++){
    float w = WT[j*HID + k];
    #pragma unroll
    for (int m = 0; m < 16; m++) acc[m] += xp[(size_t)m*HID + j] * w;
  }
  #pragma unroll
  for (int m = 0; m < 16; m++){
    float v = acc[m];
    if (do_tanh) v = tanhf(v);
    out[(n0+m)*HID + k] = v;
  }
}

extern "C" void kernel_launch(void* const* d_in, const int* in_sizes, int n_in,
                              void* d_out, int out_size, void* d_ws, size_t ws_size,
                              hipStream_t stream){
  const float* inputs = (const float*)d_in[0];
  const int*   edges  = (const int*)  d_in[1];
  const float* W1  = (const float*)d_in[2];
  const float* b1  = (const float*)d_in[3];
  const float* W2  = (const float*)d_in[4];
  const float* b2  = (const float*)d_in[5];
  const float* Wih = (const float*)d_in[6];
  const float* Whh = (const float*)d_in[7];
  const float* bih = (const float*)d_in[8];
  const float* bhh = (const float*)d_in[9];
  const float* ln1g = (const float*)d_in[10];
  const float* ln1b = (const float*)d_in[11];
  const float* ln2g = (const float*)d_in[12];
  const float* ln2b = (const float*)d_in[13];
  const float* Wh  = (const float*)d_in[14];
  const float* bh  = (const float*)d_in[15];
  const float* Wc  = (const float*)d_in[16];
  const float* bc  = (const float*)d_in[17];

  float* out = (float*)d_out;
  float* ws  = (float*)d_ws;

  float* dinv   = ws + OFF_DINV;
  int*   degcnt = (int*)(ws + OFF_DEG);
  int*   rowptr = (int*)(ws + OFF_ROWPTR);
  int*   cursor = (int*)(ws + OFF_CURSOR);
  int*   csrc   = (int*)(ws + OFF_CSRC);
  float* csrw   = ws + OFF_CSRW;
  float* WzT2   = ws + OFF_WZT;
  float* WhT    = ws + OFF_WHT;
  float* WcT    = ws + OFF_WCT;
  float* hbuf   = ws + OFF_HBUF;
  float* cbuf   = ws + OFF_CBUF;
  float* bufA   = ws + OFF_BUFA;
  float* bufB   = ws + OFF_BUFB;

  hipMemsetAsync(degcnt, 0, NN*sizeof(int), stream);
  hipMemsetAsync(cursor, 0, NN*sizeof(int), stream);

  k_transpose<<<256, 256, 0, stream>>>(Wih, Whh, Wh, Wc, WzT2, WhT, WcT);
  k_degcount<<<(NE+255)/256, 256, 0, stream>>>(edges, degcnt);
  k_dinv<<<(NN+255)/256, 256, 0, stream>>>(degcnt, dinv);
  k_scan<<<1, 1024, 0, stream>>>(degcnt, rowptr);
  k_csrfill<<<(NE+255)/256, 256, 0, stream>>>(edges, rowptr, cursor, csrc, csrw, dinv);

  // ---- GCN, chunked over timesteps; g (post-LN2) written into d_out series region ----
  for (int c0 = 0; c0 < TSTEPS; c0 += TC){
    k_gemm1<<<(TC*NN*HID)/256, 256, 0, stream>>>(inputs, W1, bufA, c0);
    k_agg_relu<<<dim3(NN, TC), 128, 0, stream>>>(bufA, rowptr, csrc, csrw, dinv, b1, bufB);
    k_gemm2<<<(TC*NN)/16, 128, 0, stream>>>(bufB, W2, bufA);
    k_agg_ln<<<dim3(NN, TC), 128, 0, stream>>>(bufA, rowptr, csrc, csrw, dinv, b2, ln2g, ln2b, out, c0);
  }

  // ---- LSTM over time: ONE persistent kernel (node-parallel recurrence) ----
  // dynamic LDS = (2*NB*HID + NB*HID + 80) * 4 = 31040 B
  k_lstm_fused<<<NBLK, 512, 31040, stream>>>(out, WzT2, bih, bhh, ln1g, ln1b, hbuf, cbuf);

  // ---- final projections ----
  float* outHidden = out + (size_t)NN*TSTEPS*HID;
  float* outCell   = outHidden + (size_t)NN*HID;
  k_final_gemm<<<NN/16, 128, 0, stream>>>(hbuf, WhT, bh, outHidden, 1);
  k_final_gemm<<<NN/16, 128, 0, stream>>>(cbuf, WcT, bc, outCell, 0);
}

// Round 3
// 6398.595 us; speedup vs baseline: 2.8989x; 1.2509x over previous
//
#include <hip/hip_runtime.h>
#include <math.h>

#define NN 10000
#define NE 160000
#define TSTEPS 64
#define FIN 16
#define HID 128
#define TC 8          // GCN timestep chunk
#define NB 20         // LSTM nodes per block
#define RPT 5         // rows per thread (NB / 4 mg-groups)
#define NBLK 500      // NN / NB

// ---- workspace element offsets (floats/ints, all 4B) ----
#define OFF_DINV   0ul
#define OFF_DEG    16384ul
#define OFF_ROWPTR 32768ul
#define OFF_CURSOR 49152ul
#define OFF_CSRC   65536ul
#define OFF_CSRW   (OFF_CSRC + (size_t)NE)
#define OFF_WZT    (OFF_CSRW + (size_t)NE)
#define OFF_WHT    (OFF_WZT + 131072ul)
#define OFF_WCT    (OFF_WHT + 16384ul)
#define OFF_HBUF   (OFF_WCT + 16384ul)
#define OFF_CBUF   (OFF_HBUF + (size_t)NN*HID)
#define OFF_BUFA   (OFF_CBUF + (size_t)NN*HID + 16384ul)
#define OFF_BUFB   (OFF_BUFA + (size_t)TC*NN*HID)

// fast transcendentals: v_exp_f32 + v_rcp_f32 (~1-2 ulp, branch-free)
__device__ __forceinline__ float fsig(float x){
  return __builtin_amdgcn_rcpf(1.f + __expf(-x));
}
__device__ __forceinline__ float ftanh(float x){
  // tanh(x) = 1 - 2/(1+e^{2x}); e^{2x}=inf -> rcp=0 -> 1; e^{2x}=0 -> -1. Branch-free.
  return fmaf(-2.f, __builtin_amdgcn_rcpf(1.f + __expf(2.f*x)), 1.f);
}

// ---- weight layouts ----
// WzT2[(j*128 + kg)*4 + q] = Wih[q*128+kg][j]          (j in 0..127)
// WzT2[((128+j)*128 + kg)*4 + q] = Whh[q*128+kg][j]    (j in 0..127)
// so a thread owning column group kg reads ONE float4 per j covering all 4 gates,
// and the g-part rows (j=0..127) are contiguously followed by the h-part rows.
// WhT/WcT stay [j*128 + k] (j-major) for the final projections.
__global__ void k_transpose(const float* __restrict__ Wih, const float* __restrict__ Whh,
                            const float* __restrict__ Wh,  const float* __restrict__ Wc,
                            float* __restrict__ WzT2, float* __restrict__ WhT, float* __restrict__ WcT){
  int idx = blockIdx.x*blockDim.x + threadIdx.x;   // 0..65535
  int k = idx >> 7;        // 0..511  (= q*128 + kg)
  int j = idx & 127;       // 0..127
  int q  = k >> 7;         // gate 0..3
  int kg = k & 127;        // column within gate
  WzT2[((size_t)j*128 + kg)*4 + q]        = Wih[(size_t)k*HID + j];
  WzT2[((size_t)(128+j)*128 + kg)*4 + q]  = Whh[(size_t)k*HID + j];
  if (k < HID){
    WhT[(size_t)j*HID + k] = Wh[(size_t)k*HID + j];
    WcT[(size_t)j*HID + k] = Wc[(size_t)k*HID + j];
  }
}

__global__ void k_degcount(const int* __restrict__ edges, int* __restrict__ degcnt){
  int e = blockIdx.x*blockDim.x + threadIdx.x;
  if (e < NE) atomicAdd(&degcnt[edges[NE + e]], 1);
}

__global__ void k_dinv(const int* __restrict__ degcnt, float* __restrict__ dinv){
  int n = blockIdx.x*blockDim.x + threadIdx.x;
  if (n < NN) dinv[n] = rsqrtf((float)(degcnt[n] + 1));   // +1 self loop, always >=1
}

// single-block scan: rowptr[0]=0, rowptr[n+1]=sum(degcnt[0..n])
__global__ void k_scan(const int* __restrict__ degcnt, int* __restrict__ rowptr){
  __shared__ int sd[1024];
  __shared__ int carry;
  if (threadIdx.x == 0){ carry = 0; rowptr[0] = 0; }
  __syncthreads();
  for (int base = 0; base < NN; base += 1024){
    int i = base + threadIdx.x;
    int v = (i < NN) ? degcnt[i] : 0;
    sd[threadIdx.x] = v;
    __syncthreads();
    for (int off = 1; off < 1024; off <<= 1){
      int t = (threadIdx.x >= off) ? sd[threadIdx.x - off] : 0;
      __syncthreads();
      sd[threadIdx.x] += t;
      __syncthreads();
    }
    int incl = sd[threadIdx.x] + carry;
    if (i < NN) rowptr[i+1] = incl;
    __syncthreads();
    if (threadIdx.x == 1023) carry = incl;
    __syncthreads();
  }
}

__global__ void k_csrfill(const int* __restrict__ edges, const int* __restrict__ rowptr,
                          int* __restrict__ cursor, int* __restrict__ csrc, float* __restrict__ csrw,
                          const float* __restrict__ dinv){
  int e = blockIdx.x*blockDim.x + threadIdx.x;
  if (e >= NE) return;
  int s = edges[e];
  int d = edges[NE + e];
  int pos = rowptr[d] + atomicAdd(&cursor[d], 1);
  csrc[pos] = s;
  csrw[pos] = dinv[s] * dinv[d];
}

// x_t @ W1 for a chunk of TC timesteps: bufA[tt][n][j]
__global__ void k_gemm1(const float* __restrict__ inputs, const float* __restrict__ W1,
                        float* __restrict__ out, int c0){
  int idx = blockIdx.x*256 + threadIdx.x;    // TC*NN*HID total
  int j  = idx & 127;
  int n  = (idx >> 7) % NN;
  int tt = idx / (NN*HID);
  int t  = c0 + tt;
  const float* x = inputs + (size_t)n*TSTEPS*FIN + (size_t)t*FIN;
  float acc = 0.f;
  #pragma unroll
  for (int f = 0; f < FIN; f++) acc = fmaf(x[f], W1[f*HID + j], acc);
  out[(size_t)tt*NN*HID + (size_t)n*HID + j] = acc;
}

// CSR gather aggregate + self loop + bias + relu: bufB[tt][n][j]
__global__ void k_agg_relu(const float* __restrict__ hbuf, const int* __restrict__ rowptr,
                           const int* __restrict__ csrc, const float* __restrict__ csrw,
                           const float* __restrict__ dinv, const float* __restrict__ b1,
                           float* __restrict__ out){
  int n = blockIdx.x, tt = blockIdx.y, j = threadIdx.x;
  const float* hb = hbuf + (size_t)tt*NN*HID;
  float dn = dinv[n];
  float acc = hb[(size_t)n*HID + j] * (dn*dn);
  int beg = rowptr[n], end = rowptr[n+1];
  for (int k = beg; k < end; k++){
    int s = csrc[k]; float w = csrw[k];
    acc = fmaf(hb[(size_t)s*HID + j], w, acc);
  }
  acc += b1[j];
  out[(size_t)tt*NN*HID + (size_t)n*HID + j] = fmaxf(acc, 0.f);
}

// [rows,128] @ W[128,128] (j-major, x@W orientation)
__global__ void k_gemm2(const float* __restrict__ X, const float* __restrict__ W,
                        float* __restrict__ out){
  int k = threadIdx.x;                       // 128
  size_t r0 = (size_t)blockIdx.x * 16;
  float acc[16];
  #pragma unroll
  for (int m = 0; m < 16; m++) acc[m] = 0.f;
  const float* xp = X + r0*HID;
  #pragma unroll 4
  for (int j = 0; j < HID; j++){
    float w = W[j*HID + k];
    #pragma unroll
    for (int m = 0; m < 16; m++) acc[m] = fmaf(xp[(size_t)m*HID + j], w, acc[m]);
  }
  #pragma unroll
  for (int m = 0; m < 16; m++) out[(r0+m)*HID + k] = acc[m];
}

// aggregate layer-2 + b2, then LayerNorm(ln2); writes g into d_out series slot [n,t,:]
__global__ void k_agg_ln(const float* __restrict__ hbuf, const int* __restrict__ rowptr,
                         const int* __restrict__ csrc, const float* __restrict__ csrw,
                         const float* __restrict__ dinv, const float* __restrict__ b2,
                         const float* __restrict__ ln2g, const float* __restrict__ ln2b,
                         float* __restrict__ outg, int c0){
  __shared__ float sb[4];
  int n = blockIdx.x, tt = blockIdx.y, j = threadIdx.x;
  const float* hb = hbuf + (size_t)tt*NN*HID;
  float dn = dinv[n];
  float acc = hb[(size_t)n*HID + j] * (dn*dn);
  int beg = rowptr[n], end = rowptr[n+1];
  for (int k = beg; k < end; k++){
    int s = csrc[k]; float w = csrw[k];
    acc = fmaf(hb[(size_t)s*HID + j], w, acc);
  }
  acc += b2[j];
  // LayerNorm over 128 lanes (2 waves)
  float s1 = acc, s2 = acc*acc;
  #pragma unroll
  for (int off = 32; off; off >>= 1){
    s1 += __shfl_down(s1, off, 64);
    s2 += __shfl_down(s2, off, 64);
  }
  if ((j & 63) == 0){ sb[j>>6] = s1; sb[(j>>6)+2] = s2; }
  __syncthreads();
  float sum = sb[0]+sb[1], sum2 = sb[2]+sb[3];
  float mean = sum * (1.f/128.f);
  float var  = sum2 * (1.f/128.f) - mean*mean;
  float rs   = rsqrtf(var + 1e-5f);
  int t = c0 + tt;
  outg[(size_t)n*TSTEPS*HID + (size_t)t*HID + j] = (acc - mean)*rs*ln2g[j] + ln2b[j];
}

// ---------------------------------------------------------------------------
// Persistent fused LSTM v3: same structure as v2 (gate-interleaved columns,
// pointwise in-register), with codegen surgery on the GEMM:
//  - explicit fmaf chains into acc[r][q]  (pure FMA, 20 independent chains)
//  - two weight base pointers so all global offsets fit the 13-bit immediate
//  - #pragma unroll 4 so LDS offsets fold into DS immediates and weight loads
//    pipeline over the FMA block
//  - fast sig/tanh via v_exp_f32 + v_rcp_f32
// ---------------------------------------------------------------------------
__global__ __launch_bounds__(512, 4)
void k_lstm_fused(float* series,                       // d_out: in=g[n][t][128], out=LN1(h)
                  const float* __restrict__ WzT2,      // [256][128][4] gate-interleaved
                  const float* __restrict__ bih, const float* __restrict__ bhh,
                  const float* __restrict__ ln1g, const float* __restrict__ ln1b,
                  float* __restrict__ hOut, float* __restrict__ cOut){
  extern __shared__ float smem[];
  float* gb = smem;                 // [2][NB][128] = 5120 f
  float* hs = smem + 2*NB*HID;      // [NB][128]    = 2560 f
  float* sb = smem + 3*NB*HID;      // [8 waves][RPT][2] = 80 f

  const int tid = threadIdx.x;
  const int kg  = tid & 127;        // column within gate
  const int mg  = tid >> 7;         // row group 0..3
  const int wv  = tid >> 6;         // wave 0..7
  const int n0  = blockIdx.x * NB;

  const float4* __restrict__ wbase = ((const float4*)WzT2) + kg;  // row stride 128 float4

  float4 bs;
  bs.x = bih[      kg] + bhh[      kg];
  bs.y = bih[128 + kg] + bhh[128 + kg];
  bs.z = bih[256 + kg] + bhh[256 + kg];
  bs.w = bih[384 + kg] + bhh[384 + kg];
  const float lg = ln1g[kg], lb = ln1b[kg];

  float creg[RPT];
  #pragma unroll
  for (int r = 0; r < RPT; r++) creg[r] = 0.f;

  // h0 = 0
  #pragma unroll
  for (int i = 0; i < RPT; i++) hs[i*512 + tid] = 0.f;

  // stage g(0)
  #pragma unroll
  for (int i = 0; i < RPT; i++){
    int flat = i*512 + tid; int m = flat >> 7; int j = flat & 127;
    gb[flat] = series[(size_t)(n0+m)*TSTEPS*HID + j];
  }
  __syncthreads();

  for (int t = 0; t < TSTEPS; t++){
    const float* gop = gb + (t & 1)*(NB*HID) + mg*RPT*HID;
    const float* hop = hs + mg*RPT*HID;

    // issue next-step g loads early; LDS-write them late (T14)
    float pre[RPT];
    const bool has_next = (t + 1 < TSTEPS);
    if (has_next){
      #pragma unroll
      for (int i = 0; i < RPT; i++){
        int flat = i*512 + tid; int m = flat >> 7; int j = flat & 127;
        pre[i] = series[(size_t)(n0+m)*TSTEPS*HID + (size_t)(t+1)*HID + j];
      }
    }

    float acc[RPT][4];
    #pragma unroll
    for (int r = 0; r < RPT; r++){
      acc[r][0] = bs.x; acc[r][1] = bs.y; acc[r][2] = bs.z; acc[r][3] = bs.w;
    }

    // ---- GEMM g-part: acc[r][q] += sum_j g[m][j] * Wih[q*128+kg][j]
    {
      const float4* wpA = wbase;            // rows j, j+1   -> offsets 0, 2048B
      const float4* wpB = wbase + 256;      // rows j+2, j+3 -> offsets 0, 2048B
      #pragma unroll 4
      for (int j4 = 0; j4 < 32; j4++){
        const float4 w0 = wpA[0];
        const float4 w1 = wpA[128];
        const float4 w2 = wpB[0];
        const float4 w3 = wpB[128];
        wpA += 512; wpB += 512;
        const int j = j4*4;
        #pragma unroll
        for (int r = 0; r < RPT; r++){
          const float4 v = *(const float4*)(gop + r*HID + j);
          acc[r][0] = fmaf(v.x, w0.x, acc[r][0]);
          acc[r][0] = fmaf(v.y, w1.x, acc[r][0]);
          acc[r][0] = fmaf(v.z, w2.x, acc[r][0]);
          acc[r][0] = fmaf(v.w, w3.x, acc[r][0]);
          acc[r][1] = fmaf(v.x, w0.y, acc[r][1]);
          acc[r][1] = fmaf(v.y, w1.y, acc[r][1]);
          acc[r][1] = fmaf(v.z, w2.y, acc[r][1]);
          acc[r][1] = fmaf(v.w, w3.y, acc[r][1]);
          acc[r][2] = fmaf(v.x, w0.z, acc[r][2]);
          acc[r][2] = fmaf(v.y, w1.z, acc[r][2]);
          acc[r][2] = fmaf(v.z, w2.z, acc[r][2]);
          acc[r][2] = fmaf(v.w, w3.z, acc[r][2]);
          acc[r][3] = fmaf(v.x, w0.w, acc[r][3]);
          acc[r][3] = fmaf(v.y, w1.w, acc[r][3]);
          acc[r][3] = fmaf(v.z, w2.w, acc[r][3]);
          acc[r][3] = fmaf(v.w, w3.w, acc[r][3]);
        }
      }
    }
    // ---- GEMM h-part: acc[r][q] += sum_j h[m][j] * Whh[q*128+kg][j]
    {
      const float4* wpA = wbase + 128*128;      // h rows start at j-row 128
      const float4* wpB = wpA + 256;
      #pragma unroll 4
      for (int j4 = 0; j4 < 32; j4++){
        const float4 w0 = wpA[0];
        const float4 w1 = wpA[128];
        const float4 w2 = wpB[0];
        const float4 w3 = wpB[128];
        wpA += 512; wpB += 512;
        const int j = j4*4;
        #pragma unroll
        for (int r = 0; r < RPT; r++){
          const float4 v = *(const float4*)(hop + r*HID + j);
          acc[r][0] = fmaf(v.x, w0.x, acc[r][0]);
          acc[r][0] = fmaf(v.y, w1.x, acc[r][0]);
          acc[r][0] = fmaf(v.z, w2.x, acc[r][0]);
          acc[r][0] = fmaf(v.w, w3.x, acc[r][0]);
          acc[r][1] = fmaf(v.x, w0.y, acc[r][1]);
          acc[r][1] = fmaf(v.y, w1.y, acc[r][1]);
          acc[r][1] = fmaf(v.z, w2.y, acc[r][1]);
          acc[r][1] = fmaf(v.w, w3.y, acc[r][1]);
          acc[r][2] = fmaf(v.x, w0.z, acc[r][2]);
          acc[r][2] = fmaf(v.y, w1.z, acc[r][2]);
          acc[r][2] = fmaf(v.z, w2.z, acc[r][2]);
          acc[r][2] = fmaf(v.w, w3.z, acc[r][2]);
          acc[r][3] = fmaf(v.x, w0.w, acc[r][3]);
          acc[r][3] = fmaf(v.y, w1.w, acc[r][3]);
          acc[r][3] = fmaf(v.z, w2.w, acc[r][3]);
          acc[r][3] = fmaf(v.w, w3.w, acc[r][3]);
        }
      }
    }
    __syncthreads();   // all reads of hs/gcur done

    // ---- pointwise + per-wave LN partials (all in registers)
    float hv[RPT];
    #pragma unroll
    for (int r = 0; r < RPT; r++){
      const int m = mg*RPT + r;
      const float cn = fsig(acc[r][1])*creg[r] + fsig(acc[r][0])*ftanh(acc[r][2]);
      const float hn = fsig(acc[r][3])*ftanh(cn);
      creg[r] = cn;
      hv[r] = hn;
      hs[m*HID + kg] = hn;
      float s1 = hn, s2 = hn*hn;
      #pragma unroll
      for (int off = 1; off < 64; off <<= 1){
        s1 += __shfl_xor(s1, off, 64);
        s2 += __shfl_xor(s2, off, 64);
      }
      if ((tid & 63) == 0){
        sb[wv*(RPT*2) + r*2    ] = s1;
        sb[wv*(RPT*2) + r*2 + 1] = s2;
      }
    }
    // land the g(t+1) prefetch
    if (has_next){
      float* gn = gb + ((t+1) & 1)*(NB*HID);
      #pragma unroll
      for (int i = 0; i < RPT; i++) gn[i*512 + tid] = pre[i];
    }
    __syncthreads();   // hs, sb, gn visible

    // ---- LN combine across the wave pair + series write
    #pragma unroll
    for (int r = 0; r < RPT; r++){
      const int m = mg*RPT + r;
      const float s1 = sb[(2*mg  )*(RPT*2) + r*2    ] + sb[(2*mg+1)*(RPT*2) + r*2    ];
      const float s2 = sb[(2*mg  )*(RPT*2) + r*2 + 1] + sb[(2*mg+1)*(RPT*2) + r*2 + 1];
      const float mean = s1 * (1.f/128.f);
      const float var  = s2 * (1.f/128.f) - mean*mean;
      const float rs   = rsqrtf(var + 1e-5f);
      series[(size_t)(n0+m)*TSTEPS*HID + (size_t)t*HID + kg] = (hv[r] - mean)*rs*lg + lb;
    }
    if (t == TSTEPS-1){
      #pragma unroll
      for (int r = 0; r < RPT; r++){
        const int m = mg*RPT + r;
        hOut[(size_t)(n0+m)*HID + kg] = hv[r];
        cOut[(size_t)(n0+m)*HID + kg] = creg[r];
      }
    }
  }
}

// out[n,k] = act(b[k] + X[n,:]@WT[:,k]); WT is [128,128] j-major
__global__ void k_final_gemm(const float* __restrict__ X, const float* __restrict__ WT,
                             const float* __restrict__ b, float* __restrict__ out, int do_tanh){
  int k = threadIdx.x;
  size_t n0 = (size_t)blockIdx.x * 16;
  float acc[16];
  float bb = b[k];
  #pragma unroll
  for (int m = 0; m < 16; m++) acc[m] = bb;
  const float* xp = X + n0*HID;
  #pragma unroll 4
  for (int j = 0; j < HID; j++){
    float w = WT[j*HID + k];
    #pragma unroll
    for (int m = 0; m < 16; m++) acc[m] = fmaf(xp[(size_t)m*HID + j], w, acc[m]);
  }
  #pragma unroll
  for (int m = 0; m < 16; m++){
    float v = acc[m];
    if (do_tanh) v = tanhf(v);
    out[(n0+m)*HID + k] = v;
  }
}

extern "C" void kernel_launch(void* const* d_in, const int* in_sizes, int n_in,
                              void* d_out, int out_size, void* d_ws, size_t ws_size,
                              hipStream_t stream){
  const float* inputs = (const float*)d_in[0];
  const int*   edges  = (const int*)  d_in[1];
  const float* W1  = (const float*)d_in[2];
  const float* b1  = (const float*)d_in[3];
  const float* W2  = (const float*)d_in[4];
  const float* b2  = (const float*)d_in[5];
  const float* Wih = (const float*)d_in[6];
  const float* Whh = (const float*)d_in[7];
  const float* bih = (const float*)d_in[8];
  const float* bhh = (const float*)d_in[9];
  const float* ln1g = (const float*)d_in[10];
  const float* ln1b = (const float*)d_in[11];
  const float* ln2g = (const float*)d_in[12];
  const float* ln2b = (const float*)d_in[13];
  const float* Wh  = (const float*)d_in[14];
  const float* bh  = (const float*)d_in[15];
  const float* Wc  = (const float*)d_in[16];
  const float* bc  = (const float*)d_in[17];

  float* out = (float*)d_out;
  float* ws  = (float*)d_ws;

  float* dinv   = ws + OFF_DINV;
  int*   degcnt = (int*)(ws + OFF_DEG);
  int*   rowptr = (int*)(ws + OFF_ROWPTR);
  int*   cursor = (int*)(ws + OFF_CURSOR);
  int*   csrc   = (int*)(ws + OFF_CSRC);
  float* csrw   = ws + OFF_CSRW;
  float* WzT2   = ws + OFF_WZT;
  float* WhT    = ws + OFF_WHT;
  float* WcT    = ws + OFF_WCT;
  float* hbuf   = ws + OFF_HBUF;
  float* cbuf   = ws + OFF_CBUF;
  float* bufA   = ws + OFF_BUFA;
  float* bufB   = ws + OFF_BUFB;

  hipMemsetAsync(degcnt, 0, NN*sizeof(int), stream);
  hipMemsetAsync(cursor, 0, NN*sizeof(int), stream);

  k_transpose<<<256, 256, 0, stream>>>(Wih, Whh, Wh, Wc, WzT2, WhT, WcT);
  k_degcount<<<(NE+255)/256, 256, 0, stream>>>(edges, degcnt);
  k_dinv<<<(NN+255)/256, 256, 0, stream>>>(degcnt, dinv);
  k_scan<<<1, 1024, 0, stream>>>(degcnt, rowptr);
  k_csrfill<<<(NE+255)/256, 256, 0, stream>>>(edges, rowptr, cursor, csrc, csrw, dinv);

  // ---- GCN, chunked over timesteps; g (post-LN2) written into d_out series region ----
  for (int c0 = 0; c0 < TSTEPS; c0 += TC){
    k_gemm1<<<(TC*NN*HID)/256, 256, 0, stream>>>(inputs, W1, bufA, c0);
    k_agg_relu<<<dim3(NN, TC), 128, 0, stream>>>(bufA, rowptr, csrc, csrw, dinv, b1, bufB);
    k_gemm2<<<(TC*NN)/16, 128, 0, stream>>>(bufB, W2, bufA);
    k_agg_ln<<<dim3(NN, TC), 128, 0, stream>>>(bufA, rowptr, csrc, csrw, dinv, b2, ln2g, ln2b, out, c0);
  }

  // ---- LSTM over time: ONE persistent kernel (node-parallel recurrence) ----
  // dynamic LDS = (2*NB*HID + NB*HID + 80) * 4 = 31040 B
  k_lstm_fused<<<NBLK, 512, 31040, stream>>>(out, WzT2, bih, bhh, ln1g, ln1b, hbuf, cbuf);

  // ---- final projections ----
  float* outHidden = out + (size_t)NN*TSTEPS*HID;
  float* outCell   = outHidden + (size_t)NN*HID;
  k_final_gemm<<<NN/16, 128, 0, stream>>>(hbuf, WhT, bh, outHidden, 1);
  k_final_gemm<<<NN/16, 128, 0, stream>>>(cbuf, WcT, bc, outCell, 0);
}

// Round 4
// 6002.760 us; speedup vs baseline: 3.0901x; 1.0659x over previous
//
#include <hip/hip_runtime.h>
#include <math.h>

#define NN 10000
#define NE 160000
#define TSTEPS 64
#define FIN 16
#define HID 128
#define TC 8          // GCN timestep chunk
#define NB 20         // LSTM nodes per block
#define RPT 5         // rows per thread (NB / 4 mg-groups)
#define NBLK 500      // NN / NB

// ---- workspace element offsets (floats/ints, all 4B) ----
#define OFF_DINV   0ul
#define OFF_DEG    16384ul
#define OFF_ROWPTR 32768ul
#define OFF_CURSOR 49152ul
#define OFF_CSRC   65536ul
#define OFF_CSRW   (OFF_CSRC + (size_t)NE)
#define OFF_WZT    (OFF_CSRW + (size_t)NE)
#define OFF_WHT    (OFF_WZT + 131072ul)
#define OFF_WCT    (OFF_WHT + 16384ul)
#define OFF_HBUF   (OFF_WCT + 16384ul)
#define OFF_CBUF   (OFF_HBUF + (size_t)NN*HID)
#define OFF_BUFA   (OFF_CBUF + (size_t)NN*HID + 16384ul)
#define OFF_BUFB   (OFF_BUFA + (size_t)TC*NN*HID)

// fast transcendentals: v_exp_f32 + v_rcp_f32 (~1-2 ulp, branch-free)
__device__ __forceinline__ float fsig(float x){
  return __builtin_amdgcn_rcpf(1.f + __expf(-x));
}
__device__ __forceinline__ float ftanh(float x){
  // tanh(x) = 1 - 2/(1+e^{2x}); e^{2x}=inf -> rcp=0 -> 1; e^{2x}=0 -> -1. Branch-free.
  return fmaf(-2.f, __builtin_amdgcn_rcpf(1.f + __expf(2.f*x)), 1.f);
}

// ---- weight layouts ----
// WzT2[(j*128 + kg)*4 + q] = Wih[q*128+kg][j]          (j in 0..127)
// WzT2[((128+j)*128 + kg)*4 + q] = Whh[q*128+kg][j]    (j in 0..127)
// so a thread owning column group kg reads ONE float4 per j covering all 4 gates,
// and the g-part rows (j=0..127) are contiguously followed by the h-part rows.
// WhT/WcT stay [j*128 + k] (j-major) for the final projections.
__global__ void k_transpose(const float* __restrict__ Wih, const float* __restrict__ Whh,
                            const float* __restrict__ Wh,  const float* __restrict__ Wc,
                            float* __restrict__ WzT2, float* __restrict__ WhT, float* __restrict__ WcT){
  int idx = blockIdx.x*blockDim.x + threadIdx.x;   // 0..65535
  int k = idx >> 7;        // 0..511  (= q*128 + kg)
  int j = idx & 127;       // 0..127
  int q  = k >> 7;         // gate 0..3
  int kg = k & 127;        // column within gate
  WzT2[((size_t)j*128 + kg)*4 + q]        = Wih[(size_t)k*HID + j];
  WzT2[((size_t)(128+j)*128 + kg)*4 + q]  = Whh[(size_t)k*HID + j];
  if (k < HID){
    WhT[(size_t)j*HID + k] = Wh[(size_t)k*HID + j];
    WcT[(size_t)j*HID + k] = Wc[(size_t)k*HID + j];
  }
}

__global__ void k_degcount(const int* __restrict__ edges, int* __restrict__ degcnt){
  int e = blockIdx.x*blockDim.x + threadIdx.x;
  if (e < NE) atomicAdd(&degcnt[edges[NE + e]], 1);
}

__global__ void k_dinv(const int* __restrict__ degcnt, float* __restrict__ dinv){
  int n = blockIdx.x*blockDim.x + threadIdx.x;
  if (n < NN) dinv[n] = rsqrtf((float)(degcnt[n] + 1));   // +1 self loop, always >=1
}

// single-block scan: rowptr[0]=0, rowptr[n+1]=sum(degcnt[0..n])
__global__ void k_scan(const int* __restrict__ degcnt, int* __restrict__ rowptr){
  __shared__ int sd[1024];
  __shared__ int carry;
  if (threadIdx.x == 0){ carry = 0; rowptr[0] = 0; }
  __syncthreads();
  for (int base = 0; base < NN; base += 1024){
    int i = base + threadIdx.x;
    int v = (i < NN) ? degcnt[i] : 0;
    sd[threadIdx.x] = v;
    __syncthreads();
    for (int off = 1; off < 1024; off <<= 1){
      int t = (threadIdx.x >= off) ? sd[threadIdx.x - off] : 0;
      __syncthreads();
      sd[threadIdx.x] += t;
      __syncthreads();
    }
    int incl = sd[threadIdx.x] + carry;
    if (i < NN) rowptr[i+1] = incl;
    __syncthreads();
    if (threadIdx.x == 1023) carry = incl;
    __syncthreads();
  }
}

__global__ void k_csrfill(const int* __restrict__ edges, const int* __restrict__ rowptr,
                          int* __restrict__ cursor, int* __restrict__ csrc, float* __restrict__ csrw,
                          const float* __restrict__ dinv){
  int e = blockIdx.x*blockDim.x + threadIdx.x;
  if (e >= NE) return;
  int s = edges[e];
  int d = edges[NE + e];
  int pos = rowptr[d] + atomicAdd(&cursor[d], 1);
  csrc[pos] = s;
  csrw[pos] = dinv[s] * dinv[d];
}

// x_t @ W1 for a chunk of TC timesteps: bufA[tt][n][j]
__global__ void k_gemm1(const float* __restrict__ inputs, const float* __restrict__ W1,
                        float* __restrict__ out, int c0){
  int idx = blockIdx.x*256 + threadIdx.x;    // TC*NN*HID total
  int j  = idx & 127;
  int n  = (idx >> 7) % NN;
  int tt = idx / (NN*HID);
  int t  = c0 + tt;
  const float* x = inputs + (size_t)n*TSTEPS*FIN + (size_t)t*FIN;
  float acc = 0.f;
  #pragma unroll
  for (int f = 0; f < FIN; f++) acc = fmaf(x[f], W1[f*HID + j], acc);
  out[(size_t)tt*NN*HID + (size_t)n*HID + j] = acc;
}

// CSR gather aggregate + self loop + bias + relu: bufB[tt][n][j]
// 4-way edge unroll: 4 independent gather streams per block (MLP in the
// latency-bound phase); index loads are wave-uniform broadcasts.
__global__ void k_agg_relu(const float* __restrict__ hbuf, const int* __restrict__ rowptr,
                           const int* __restrict__ csrc, const float* __restrict__ csrw,
                           const float* __restrict__ dinv, const float* __restrict__ b1,
                           float* __restrict__ out){
  int n = blockIdx.x, tt = blockIdx.y, j = threadIdx.x;
  const float* hb = hbuf + (size_t)tt*NN*HID;
  float dn = dinv[n];
  float a0 = hb[(size_t)n*HID + j] * (dn*dn);
  float a1 = 0.f, a2 = 0.f, a3 = 0.f;
  int beg = rowptr[n], end = rowptr[n+1];
  int k = beg;
  for (; k + 3 < end; k += 4){
    int   s0 = csrc[k],   s1 = csrc[k+1], s2 = csrc[k+2], s3 = csrc[k+3];
    float w0 = csrw[k],   w1 = csrw[k+1], w2 = csrw[k+2], w3 = csrw[k+3];
    a0 = fmaf(hb[(size_t)s0*HID + j], w0, a0);
    a1 = fmaf(hb[(size_t)s1*HID + j], w1, a1);
    a2 = fmaf(hb[(size_t)s2*HID + j], w2, a2);
    a3 = fmaf(hb[(size_t)s3*HID + j], w3, a3);
  }
  for (; k < end; k++){
    a0 = fmaf(hb[(size_t)csrc[k]*HID + j], csrw[k], a0);
  }
  float acc = (a0 + a1) + (a2 + a3) + b1[j];
  out[(size_t)tt*NN*HID + (size_t)n*HID + j] = fmaxf(acc, 0.f);
}

// [rows,128] @ W[128,128] (j-major, x@W orientation)
__global__ void k_gemm2(const float* __restrict__ X, const float* __restrict__ W,
                        float* __restrict__ out){
  int k = threadIdx.x;                       // 128
  size_t r0 = (size_t)blockIdx.x * 16;
  float acc[16];
  #pragma unroll
  for (int m = 0; m < 16; m++) acc[m] = 0.f;
  const float* xp = X + r0*HID;
  #pragma unroll 4
  for (int j = 0; j < HID; j++){
    float w = W[j*HID + k];
    #pragma unroll
    for (int m = 0; m < 16; m++) acc[m] = fmaf(xp[(size_t)m*HID + j], w, acc[m]);
  }
  #pragma unroll
  for (int m = 0; m < 16; m++) out[(r0+m)*HID + k] = acc[m];
}

// aggregate layer-2 + b2, then LayerNorm(ln2); writes g into d_out series slot [n,t,:]
// same 4-way edge unroll as k_agg_relu.
__global__ void k_agg_ln(const float* __restrict__ hbuf, const int* __restrict__ rowptr,
                         const int* __restrict__ csrc, const float* __restrict__ csrw,
                         const float* __restrict__ dinv, const float* __restrict__ b2,
                         const float* __restrict__ ln2g, const float* __restrict__ ln2b,
                         float* __restrict__ outg, int c0){
  __shared__ float sb[4];
  int n = blockIdx.x, tt = blockIdx.y, j = threadIdx.x;
  const float* hb = hbuf + (size_t)tt*NN*HID;
  float dn = dinv[n];
  float a0 = hb[(size_t)n*HID + j] * (dn*dn);
  float a1 = 0.f, a2 = 0.f, a3 = 0.f;
  int beg = rowptr[n], end = rowptr[n+1];
  int k = beg;
  for (; k + 3 < end; k += 4){
    int   s0 = csrc[k],   s1 = csrc[k+1], s2 = csrc[k+2], s3 = csrc[k+3];
    float w0 = csrw[k],   w1 = csrw[k+1], w2 = csrw[k+2], w3 = csrw[k+3];
    a0 = fmaf(hb[(size_t)s0*HID + j], w0, a0);
    a1 = fmaf(hb[(size_t)s1*HID + j], w1, a1);
    a2 = fmaf(hb[(size_t)s2*HID + j], w2, a2);
    a3 = fmaf(hb[(size_t)s3*HID + j], w3, a3);
  }
  for (; k < end; k++){
    a0 = fmaf(hb[(size_t)csrc[k]*HID + j], csrw[k], a0);
  }
  float acc = (a0 + a1) + (a2 + a3) + b2[j];
  // LayerNorm over 128 lanes (2 waves)
  float s1 = acc, s2 = acc*acc;
  #pragma unroll
  for (int off = 32; off; off >>= 1){
    s1 += __shfl_down(s1, off, 64);
    s2 += __shfl_down(s2, off, 64);
  }
  if ((j & 63) == 0){ sb[j>>6] = s1; sb[(j>>6)+2] = s2; }
  __syncthreads();
  float sum = sb[0]+sb[1], sum2 = sb[2]+sb[3];
  float mean = sum * (1.f/128.f);
  float var  = sum2 * (1.f/128.f) - mean*mean;
  float rs   = rsqrtf(var + 1e-5f);
  int t = c0 + tt;
  outg[(size_t)n*TSTEPS*HID + (size_t)t*HID + j] = (acc - mean)*rs*ln2g[j] + ln2b[j];
}

// ---------------------------------------------------------------------------
// Persistent fused LSTM v4: v3 + explicit register double-buffering of the
// weight stream. Next j4 group's 4 float4 are loaded into separate regs
// BEFORE the 80 FMAs on the current group -> vmcnt wait overlaps FMA issue.
// Occupancy is grid-limited (~3.4 waves/SIMD), so VGPR up to 128 is free.
// g-rows (0..127) and h-rows (128..255) are contiguous in WzT2, so the
// prefetch carries seamlessly across the g->h boundary; the final h-loop
// prefetch reads ~8KB past WzT2 into the WhT workspace region (valid
// memory, values discarded).
// ---------------------------------------------------------------------------
__global__ __launch_bounds__(512, 4)
void k_lstm_fused(float* series,                       // d_out: in=g[n][t][128], out=LN1(h)
                  const float* __restrict__ WzT2,      // [256][128][4] gate-interleaved
                  const float* __restrict__ bih, const float* __restrict__ bhh,
                  const float* __restrict__ ln1g, const float* __restrict__ ln1b,
                  float* __restrict__ hOut, float* __restrict__ cOut){
  extern __shared__ float smem[];
  float* gb = smem;                 // [2][NB][128] = 5120 f
  float* hs = smem + 2*NB*HID;      // [NB][128]    = 2560 f
  float* sb = smem + 3*NB*HID;      // [8 waves][RPT][2] = 80 f

  const int tid = threadIdx.x;
  const int kg  = tid & 127;        // column within gate
  const int mg  = tid >> 7;         // row group 0..3
  const int wv  = tid >> 6;         // wave 0..7
  const int n0  = blockIdx.x * NB;

  const float4* __restrict__ wbase = ((const float4*)WzT2) + kg;  // row stride 128 float4

  float4 bs;
  bs.x = bih[      kg] + bhh[      kg];
  bs.y = bih[128 + kg] + bhh[128 + kg];
  bs.z = bih[256 + kg] + bhh[256 + kg];
  bs.w = bih[384 + kg] + bhh[384 + kg];
  const float lg = ln1g[kg], lb = ln1b[kg];

  float creg[RPT];
  #pragma unroll
  for (int r = 0; r < RPT; r++) creg[r] = 0.f;

  // h0 = 0
  #pragma unroll
  for (int i = 0; i < RPT; i++) hs[i*512 + tid] = 0.f;

  // stage g(0)
  #pragma unroll
  for (int i = 0; i < RPT; i++){
    int flat = i*512 + tid; int m = flat >> 7; int j = flat & 127;
    gb[flat] = series[(size_t)(n0+m)*TSTEPS*HID + j];
  }
  __syncthreads();

  for (int t = 0; t < TSTEPS; t++){
    const float* gop = gb + (t & 1)*(NB*HID) + mg*RPT*HID;
    const float* hop = hs + mg*RPT*HID;

    // issue next-step g loads early; LDS-write them late (T14)
    float pre[RPT];
    const bool has_next = (t + 1 < TSTEPS);
    if (has_next){
      #pragma unroll
      for (int i = 0; i < RPT; i++){
        int flat = i*512 + tid; int m = flat >> 7; int j = flat & 127;
        pre[i] = series[(size_t)(n0+m)*TSTEPS*HID + (size_t)(t+1)*HID + j];
      }
    }

    float acc[RPT][4];
    #pragma unroll
    for (int r = 0; r < RPT; r++){
      acc[r][0] = bs.x; acc[r][1] = bs.y; acc[r][2] = bs.z; acc[r][3] = bs.w;
    }

    // weight stream: register double-buffer, rows advance 4 at a time.
    const float4* wpA = wbase;            // rows 4i, 4i+1   (offsets 0, 2048B)
    const float4* wpB = wbase + 256;      // rows 4i+2, 4i+3 (offsets 0, 2048B)
    float4 w0 = wpA[0], w1 = wpA[128], w2 = wpB[0], w3 = wpB[128];
    wpA += 512; wpB += 512;

    // ---- GEMM g-part: rows 0..127 of WzT2, operand from gop
    #pragma unroll 4
    for (int j4 = 0; j4 < 32; j4++){
      const float4 nw0 = wpA[0];
      const float4 nw1 = wpA[128];
      const float4 nw2 = wpB[0];
      const float4 nw3 = wpB[128];
      wpA += 512; wpB += 512;
      const int j = j4*4;
      #pragma unroll
      for (int r = 0; r < RPT; r++){
        const float4 v = *(const float4*)(gop + r*HID + j);
        acc[r][0] = fmaf(v.x, w0.x, acc[r][0]);
        acc[r][0] = fmaf(v.y, w1.x, acc[r][0]);
        acc[r][0] = fmaf(v.z, w2.x, acc[r][0]);
        acc[r][0] = fmaf(v.w, w3.x, acc[r][0]);
        acc[r][1] = fmaf(v.x, w0.y, acc[r][1]);
        acc[r][1] = fmaf(v.y, w1.y, acc[r][1]);
        acc[r][1] = fmaf(v.z, w2.y, acc[r][1]);
        acc[r][1] = fmaf(v.w, w3.y, acc[r][1]);
        acc[r][2] = fmaf(v.x, w0.z, acc[r][2]);
        acc[r][2] = fmaf(v.y, w1.z, acc[r][2]);
        acc[r][2] = fmaf(v.z, w2.z, acc[r][2]);
        acc[r][2] = fmaf(v.w, w3.z, acc[r][2]);
        acc[r][3] = fmaf(v.x, w0.w, acc[r][3]);
        acc[r][3] = fmaf(v.y, w1.w, acc[r][3]);
        acc[r][3] = fmaf(v.z, w2.w, acc[r][3]);
        acc[r][3] = fmaf(v.w, w3.w, acc[r][3]);
      }
      w0 = nw0; w1 = nw1; w2 = nw2; w3 = nw3;
    }
    // at this point w holds rows 128..131 (first h rows) -- seamless carry.

    // ---- GEMM h-part: rows 128..255 of WzT2, operand from hop
    #pragma unroll 4
    for (int j4 = 0; j4 < 32; j4++){
      const float4 nw0 = wpA[0];      // last iter reads past WzT2 into WhT: valid ws memory, discarded
      const float4 nw1 = wpA[128];
      const float4 nw2 = wpB[0];
      const float4 nw3 = wpB[128];
      wpA += 512; wpB += 512;
      const int j = j4*4;
      #pragma unroll
      for (int r = 0; r < RPT; r++){
        const float4 v = *(const float4*)(hop + r*HID + j);
        acc[r][0] = fmaf(v.x, w0.x, acc[r][0]);
        acc[r][0] = fmaf(v.y, w1.x, acc[r][0]);
        acc[r][0] = fmaf(v.z, w2.x, acc[r][0]);
        acc[r][0] = fmaf(v.w, w3.x, acc[r][0]);
        acc[r][1] = fmaf(v.x, w0.y, acc[r][1]);
        acc[r][1] = fmaf(v.y, w1.y, acc[r][1]);
        acc[r][1] = fmaf(v.z, w2.y, acc[r][1]);
        acc[r][1] = fmaf(v.w, w3.y, acc[r][1]);
        acc[r][2] = fmaf(v.x, w0.z, acc[r][2]);
        acc[r][2] = fmaf(v.y, w1.z, acc[r][2]);
        acc[r][2] = fmaf(v.z, w2.z, acc[r][2]);
        acc[r][2] = fmaf(v.w, w3.z, acc[r][2]);
        acc[r][3] = fmaf(v.x, w0.w, acc[r][3]);
        acc[r][3] = fmaf(v.y, w1.w, acc[r][3]);
        acc[r][3] = fmaf(v.z, w2.w, acc[r][3]);
        acc[r][3] = fmaf(v.w, w3.w, acc[r][3]);
      }
      w0 = nw0; w1 = nw1; w2 = nw2; w3 = nw3;
    }
    __syncthreads();   // all reads of hs/gcur done

    // ---- pointwise + per-wave LN partials (all in registers)
    float hv[RPT];
    #pragma unroll
    for (int r = 0; r < RPT; r++){
      const int m = mg*RPT + r;
      const float cn = fsig(acc[r][1])*creg[r] + fsig(acc[r][0])*ftanh(acc[r][2]);
      const float hn = fsig(acc[r][3])*ftanh(cn);
      creg[r] = cn;
      hv[r] = hn;
      hs[m*HID + kg] = hn;
      float s1 = hn, s2 = hn*hn;
      #pragma unroll
      for (int off = 1; off < 64; off <<= 1){
        s1 += __shfl_xor(s1, off, 64);
        s2 += __shfl_xor(s2, off, 64);
      }
      if ((tid & 63) == 0){
        sb[wv*(RPT*2) + r*2    ] = s1;
        sb[wv*(RPT*2) + r*2 + 1] = s2;
      }
    }
    // land the g(t+1) prefetch
    if (has_next){
      float* gn = gb + ((t+1) & 1)*(NB*HID);
      #pragma unroll
      for (int i = 0; i < RPT; i++) gn[i*512 + tid] = pre[i];
    }
    __syncthreads();   // hs, sb, gn visible

    // ---- LN combine across the wave pair + series write
    #pragma unroll
    for (int r = 0; r < RPT; r++){
      const int m = mg*RPT + r;
      const float s1 = sb[(2*mg  )*(RPT*2) + r*2    ] + sb[(2*mg+1)*(RPT*2) + r*2    ];
      const float s2 = sb[(2*mg  )*(RPT*2) + r*2 + 1] + sb[(2*mg+1)*(RPT*2) + r*2 + 1];
      const float mean = s1 * (1.f/128.f);
      const float var  = s2 * (1.f/128.f) - mean*mean;
      const float rs   = rsqrtf(var + 1e-5f);
      series[(size_t)(n0+m)*TSTEPS*HID + (size_t)t*HID + kg] = (hv[r] - mean)*rs*lg + lb;
    }
    if (t == TSTEPS-1){
      #pragma unroll
      for (int r = 0; r < RPT; r++){
        const int m = mg*RPT + r;
        hOut[(size_t)(n0+m)*HID + kg] = hv[r];
        cOut[(size_t)(n0+m)*HID + kg] = creg[r];
      }
    }
  }
}

// out[n,k] = act(b[k] + X[n,:]@WT[:,k]); WT is [128,128] j-major
__global__ void k_final_gemm(const float* __restrict__ X, const float* __restrict__ WT,
                             const float* __restrict__ b, float* __restrict__ out, int do_tanh){
  int k = threadIdx.x;
  size_t n0 = (size_t)blockIdx.x * 16;
  float acc[16];
  float bb = b[k];
  #pragma unroll
  for (int m = 0; m < 16; m++) acc[m] = bb;
  const float* xp = X + n0*HID;
  #pragma unroll 4
  for (int j = 0; j < HID; j++){
    float w = WT[j*HID + k];
    #pragma unroll
    for (int m = 0; m < 16; m++) acc[m] = fmaf(xp[(size_t)m*HID + j], w, acc[m]);
  }
  #pragma unroll
  for (int m = 0; m < 16; m++){
    float v = acc[m];
    if (do_tanh) v = tanhf(v);
    out[(n0+m)*HID + k] = v;
  }
}

extern "C" void kernel_launch(void* const* d_in, const int* in_sizes, int n_in,
                              void* d_out, int out_size, void* d_ws, size_t ws_size,
                              hipStream_t stream){
  const float* inputs = (const float*)d_in[0];
  const int*   edges  = (const int*)  d_in[1];
  const float* W1  = (const float*)d_in[2];
  const float* b1  = (const float*)d_in[3];
  const float* W2  = (const float*)d_in[4];
  const float* b2  = (const float*)d_in[5];
  const float* Wih = (const float*)d_in[6];
  const float* Whh = (const float*)d_in[7];
  const float* bih = (const float*)d_in[8];
  const float* bhh = (const float*)d_in[9];
  const float* ln1g = (const float*)d_in[10];
  const float* ln1b = (const float*)d_in[11];
  const float* ln2g = (const float*)d_in[12];
  const float* ln2b = (const float*)d_in[13];
  const float* Wh  = (const float*)d_in[14];
  const float* bh  = (const float*)d_in[15];
  const float* Wc  = (const float*)d_in[16];
  const float* bc  = (const float*)d_in[17];

  float* out = (float*)d_out;
  float* ws  = (float*)d_ws;

  float* dinv   = ws + OFF_DINV;
  int*   degcnt = (int*)(ws + OFF_DEG);
  int*   rowptr = (int*)(ws + OFF_ROWPTR);
  int*   cursor = (int*)(ws + OFF_CURSOR);
  int*   csrc   = (int*)(ws + OFF_CSRC);
  float* csrw   = ws + OFF_CSRW;
  float* WzT2   = ws + OFF_WZT;
  float* WhT    = ws + OFF_WHT;
  float* WcT    = ws + OFF_WCT;
  float* hbuf   = ws + OFF_HBUF;
  float* cbuf   = ws + OFF_CBUF;
  float* bufA   = ws + OFF_BUFA;
  float* bufB   = ws + OFF_BUFB;

  hipMemsetAsync(degcnt, 0, NN*sizeof(int), stream);
  hipMemsetAsync(cursor, 0, NN*sizeof(int), stream);

  k_transpose<<<256, 256, 0, stream>>>(Wih, Whh, Wh, Wc, WzT2, WhT, WcT);
  k_degcount<<<(NE+255)/256, 256, 0, stream>>>(edges, degcnt);
  k_dinv<<<(NN+255)/256, 256, 0, stream>>>(degcnt, dinv);
  k_scan<<<1, 1024, 0, stream>>>(degcnt, rowptr);
  k_csrfill<<<(NE+255)/256, 256, 0, stream>>>(edges, rowptr, cursor, csrc, csrw, dinv);

  // ---- GCN, chunked over timesteps; g (post-LN2) written into d_out series region ----
  for (int c0 = 0; c0 < TSTEPS; c0 += TC){
    k_gemm1<<<(TC*NN*HID)/256, 256, 0, stream>>>(inputs, W1, bufA, c0);
    k_agg_relu<<<dim3(NN, TC), 128, 0, stream>>>(bufA, rowptr, csrc, csrw, dinv, b1, bufB);
    k_gemm2<<<(TC*NN)/16, 128, 0, stream>>>(bufB, W2, bufA);
    k_agg_ln<<<dim3(NN, TC), 128, 0, stream>>>(bufA, rowptr, csrc, csrw, dinv, b2, ln2g, ln2b, out, c0);
  }

  // ---- LSTM over time: ONE persistent kernel (node-parallel recurrence) ----
  // dynamic LDS = (2*NB*HID + NB*HID + 80) * 4 = 31040 B
  k_lstm_fused<<<NBLK, 512, 31040, stream>>>(out, WzT2, bih, bhh, ln1g, ln1b, hbuf, cbuf);

  // ---- final projections ----
  float* outHidden = out + (size_t)NN*TSTEPS*HID;
  float* outCell   = outHidden + (size_t)NN*HID;
  k_final_gemm<<<NN/16, 128, 0, stream>>>(hbuf, WhT, bh, outHidden, 1);
  k_final_gemm<<<NN/16, 128, 0, stream>>>(cbuf, WcT, bc, outCell, 0);
}